// Round 8
// baseline (94.208 us; speedup 1.0000x reference)
//
#include <hip/hip_runtime.h>

// Problem constants
#define S_   16384
#define T_   16384
#define B_   32
#define NEDGES (S_ * 64)       // 1,048,576
#define GP_  512               // producer blocks, 2048 edges each
#define EPG  2048              // edges per producer block
#define NBKT 512               // buckets of 32 targets
#define TPB  32                // targets per bucket
#define CAP_SRT   2560         // per-bucket records: lambda=2048, +11 sigma
#define CAP_STASH 512          // overflow records per consumer (expected ~1)

// weight = clip(att,0,1) * 0.9^delay, delay in [0,6). Exact bit-product.
__device__ __forceinline__ float edge_weight(float a, int d) {
  float w = fminf(fmaxf(a, 0.0f), 1.0f);
  float r = (d & 1) ? 0.9f : 1.0f;
  r = (d & 2) ? r * 0.81f   : r;
  r = (d & 4) ? r * 0.6561f : r;
  return w * r;
}

// ---------------------------------------------------------------------------
// K1: transpose 32 sources of spikes + LDS counting-sort of 2048 edges into
// 512 buckets + one contiguous 16 KB flush. 512 blocks x 512 thr = 2/CU.
// rec[g][i], i in [0,2048): {meta = tl<<14 | src, w_bits} grouped by bucket;
// ofse[g][bkt] = end<<16 | start.
__global__ __launch_bounds__(512) void produce(
    const float* __restrict__ spikes,
    const float* __restrict__ att,
    const int*   __restrict__ tgt,
    const int*   __restrict__ del,
    float*        __restrict__ spikesT,
    int2*         __restrict__ rec,
    unsigned int* __restrict__ ofse) {
  __shared__ float tile[32][33];        // 4.2 KB
  __shared__ int4  sbuf4[EPG / 2];      // 16 KB: 2048 int2 records
  __shared__ int   cnt5[NBKT], cur5[NBKT], sofs5[NBKT];   // 6 KB
  __shared__ int   wtot[8];
  int2* buf = (int2*)sbuf4;

  const int g   = blockIdx.x;
  const int tid = threadIdx.x;
  cnt5[tid] = 0;                        // 512 bins, 512 threads

  // transpose sources [g*32, g*32+32)
  const int s0 = g * 32;
  {
    const int x = tid & 31, y = tid >> 5;       // y = batch 0..15
    tile[x][y]      = spikes[(size_t)y        * S_ + s0 + x];
    tile[x][y + 16] = spikes[(size_t)(y + 16) * S_ + s0 + x];
  }

  // my 4 edges (held in registers through all phases)
  const int e4  = g * 512 + tid;
  int4   t = reinterpret_cast<const int4*>(tgt)[e4];
  float4 a = reinterpret_cast<const float4*>(att)[e4];
  int4   d = reinterpret_cast<const int4*>(del)[e4];
  const int src = e4 >> 4;              // (e4*4)/64: 4 consecutive edges share

  __syncthreads();                      // cnt5 + tile visible

  {
    const int b = tid & 31, j = tid >> 5;       // j 0..15
    spikesT[(size_t)(s0 + j)      * 32 + b] = tile[j][b];
    spikesT[(size_t)(s0 + j + 16) * 32 + b] = tile[j + 16][b];
  }

  // pass 1: bucket histogram
  const int bk0 = t.x >> 5, bk1 = t.y >> 5, bk2 = t.z >> 5, bk3 = t.w >> 5;
  __hip_atomic_fetch_add(&cnt5[bk0], 1, __ATOMIC_RELAXED, __HIP_MEMORY_SCOPE_WORKGROUP);
  __hip_atomic_fetch_add(&cnt5[bk1], 1, __ATOMIC_RELAXED, __HIP_MEMORY_SCOPE_WORKGROUP);
  __hip_atomic_fetch_add(&cnt5[bk2], 1, __ATOMIC_RELAXED, __HIP_MEMORY_SCOPE_WORKGROUP);
  __hip_atomic_fetch_add(&cnt5[bk3], 1, __ATOMIC_RELAXED, __HIP_MEMORY_SCOPE_WORKGROUP);
  __syncthreads();

  // exclusive scan of 512 bins: 8 waves shuffle-scan 64 each, combine
  int v = cnt5[tid];
  int incl = v;
#pragma unroll
  for (int off = 1; off < 64; off <<= 1) {
    int u = __shfl_up(incl, off);
    if ((tid & 63) >= off) incl += u;
  }
  if ((tid & 63) == 63) wtot[tid >> 6] = incl;
  __syncthreads();
  {
    int base = 0;
    const int wv = tid >> 6;
    for (int i = 0; i < wv; ++i) base += wtot[i];
    const int start = base + incl - v;
    sofs5[tid] = start;
    cur5[tid]  = start;
  }
  __syncthreads();

  // pass 2: weight + place at bucket cursor (exact sizes, no overflow)
#define PUT(BK, TL, AV, DV)                                                   \
  {                                                                           \
    int p = __hip_atomic_fetch_add(&cur5[BK], 1, __ATOMIC_RELAXED,            \
                                   __HIP_MEMORY_SCOPE_WORKGROUP);             \
    buf[p] = make_int2(((TL) << 14) | src,                                    \
                       __float_as_int(edge_weight((AV), (DV))));              \
  }
  PUT(bk0, t.x & 31, a.x, d.x)
  PUT(bk1, t.y & 31, a.y, d.y)
  PUT(bk2, t.z & 31, a.z, d.z)
  PUT(bk3, t.w & 31, a.w, d.w)
#undef PUT
  __syncthreads();

  // flush: contiguous 16 KB (1024 int4, 512 thr x 2)
  int4* recO = reinterpret_cast<int4*>(rec) + (size_t)g * (EPG / 2);
  recO[tid]       = sbuf4[tid];
  recO[tid + 512] = sbuf4[tid + 512];
  ofse[(size_t)g * NBKT + tid] =
      ((unsigned)cur5[tid] << 16) | (unsigned)sofs5[tid];    // coalesced
}

// ---------------------------------------------------------------------------
// K1b: ofse [g][bkt] -> ofseT [bkt][g] so consumers read one coalesced row.
__global__ __launch_bounds__(256) void transpose_ofse(
    const unsigned int* __restrict__ in, unsigned int* __restrict__ out) {
  __shared__ unsigned tl[32][33];
  const int x = threadIdx.x, y = threadIdx.y;   // 32, 8
  const int r0 = blockIdx.y * 32, c0 = blockIdx.x * 32;
  for (int i = y; i < 32; i += 8)
    tl[i][x] = in[(size_t)(r0 + i) * NBKT + c0 + x];
  __syncthreads();
  for (int i = y; i < 32; i += 8)
    out[(size_t)(c0 + i) * GP_ + r0 + x] = tl[x][i];
}

// ---------------------------------------------------------------------------
// K2: bucket k reads its 512 slices (4 slices per half-wave, 8-lane groups),
// histograms into 32 bins, keeps records in REGISTERS, shuffle-scans, ranks,
// scatters to srt, register-gathers, writes out directly. 512 x 512.
__global__ __launch_bounds__(512) void consume(
    const int2*  __restrict__ rec,
    const unsigned int* __restrict__ ofseT,
    const float* __restrict__ spikesT,
    float* __restrict__ out) {
  __shared__ int2  srt[CAP_SRT];        // 20 KB target-sorted
  __shared__ int2  stash[CAP_STASH];    // 4 KB overflow (n>8 tails)
  __shared__ float otile[TPB][33];      // 4.2 KB
  __shared__ unsigned sse[GP_];         // 2 KB
  __shared__ int   h32[TPB], ofs[TPB + 1], cur32[TPB];
  __shared__ int   stash_n;

  const int k   = blockIdx.x;
  const int tid = threadIdx.x;
  const int b   = tid & 31;
  const int hw  = tid >> 5;             // 0..15
  const int sub = (b >> 3);             // 0..3: which of 4 slices
  const int j   = b & 7;                // lane within slice

  if (tid < TPB) h32[tid] = 0;
  if (tid == 0)  stash_n = 0;
  sse[tid] = ofseT[(size_t)k * GP_ + tid];      // coalesced 2 KB row
  __syncthreads();

  // pass 1: read slices, histogram, keep records in registers
  int2 rr[8];
  int  rv = 0;
#pragma unroll
  for (int it = 0; it < 8; ++it) {
    const int g = it * 64 + hw * 4 + sub;
    const unsigned u = sse[g];
    const int st = (int)(u & 0xFFFF);
    const int n  = (int)(u >> 16) - st;
    const int2* slice = rec + (size_t)g * EPG + st;
    if (j < n) {
      int2 r = slice[j];
      __hip_atomic_fetch_add(&h32[(r.x >> 14) & 31], 1, __ATOMIC_RELAXED,
                             __HIP_MEMORY_SCOPE_WORKGROUP);
      rr[it] = r;
      rv |= 1 << it;
    }
    for (int j2 = j + 8; j2 < n; j2 += 8) {     // rare (P ~ 0.2% per slice)
      int2 r = slice[j2];
      __hip_atomic_fetch_add(&h32[(r.x >> 14) & 31], 1, __ATOMIC_RELAXED,
                             __HIP_MEMORY_SCOPE_WORKGROUP);
      int sp = __hip_atomic_fetch_add(&stash_n, 1, __ATOMIC_RELAXED,
                                      __HIP_MEMORY_SCOPE_WORKGROUP);
      if (sp < CAP_STASH) stash[sp] = r;
    }
  }
  __syncthreads();

  // exclusive scan of 32 target bins (wave 0)
  if (tid < 32) {
    int vv = h32[tid], ii = vv;
#pragma unroll
    for (int off = 1; off < 32; off <<= 1) {
      int uu = __shfl_up(ii, off);
      if (tid >= off) ii += uu;
    }
    ofs[tid]   = ii - vv;
    cur32[tid] = ii - vv;
    if (tid == 31) ofs[32] = ii;
  }
  __syncthreads();

  // pass 2: rank + scatter registers -> srt
#pragma unroll
  for (int it = 0; it < 8; ++it)
    if (rv & (1 << it)) {
      int2 r = rr[it];
      int p = __hip_atomic_fetch_add(&cur32[(r.x >> 14) & 31], 1,
                                     __ATOMIC_RELAXED,
                                     __HIP_MEMORY_SCOPE_WORKGROUP);
      if (p < CAP_SRT) srt[p] = r;
    }
  const int ns = min(stash_n, CAP_STASH);
  for (int i = tid; i < ns; i += 512) {
    int2 r = stash[i];
    int p = __hip_atomic_fetch_add(&cur32[(r.x >> 14) & 31], 1,
                                   __ATOMIC_RELAXED,
                                   __HIP_MEMORY_SCOPE_WORKGROUP);
    if (p < CAP_SRT) srt[p] = r;
  }
  __syncthreads();

  // gather: half-wave hw owns targets hw (acc0), hw+16 (acc1); lane = batch
  float acc0 = 0.f, acc1 = 0.f;
  {
    int e        = ofs[hw];
    const int e1 = min(ofs[hw + 1], CAP_SRT);
    for (; e + 4 <= e1; e += 4) {
      int2 r0 = srt[e], r1 = srt[e + 1], r2 = srt[e + 2], r3 = srt[e + 3];
      float s0 = spikesT[(size_t)(r0.x & 0x3FFF) * 32 + b];
      float s1 = spikesT[(size_t)(r1.x & 0x3FFF) * 32 + b];
      float s2 = spikesT[(size_t)(r2.x & 0x3FFF) * 32 + b];
      float s3 = spikesT[(size_t)(r3.x & 0x3FFF) * 32 + b];
      acc0 = fmaf(__int_as_float(r0.y), s0, acc0);
      acc0 = fmaf(__int_as_float(r1.y), s1, acc0);
      acc0 = fmaf(__int_as_float(r2.y), s2, acc0);
      acc0 = fmaf(__int_as_float(r3.y), s3, acc0);
    }
    for (; e < e1; ++e) {
      int2 r = srt[e];
      acc0 = fmaf(__int_as_float(r.y), spikesT[(size_t)(r.x & 0x3FFF) * 32 + b], acc0);
    }
  }
  {
    int e        = ofs[hw + 16];
    const int e1 = min(ofs[hw + 17], CAP_SRT);
    for (; e + 4 <= e1; e += 4) {
      int2 r0 = srt[e], r1 = srt[e + 1], r2 = srt[e + 2], r3 = srt[e + 3];
      float s0 = spikesT[(size_t)(r0.x & 0x3FFF) * 32 + b];
      float s1 = spikesT[(size_t)(r1.x & 0x3FFF) * 32 + b];
      float s2 = spikesT[(size_t)(r2.x & 0x3FFF) * 32 + b];
      float s3 = spikesT[(size_t)(r3.x & 0x3FFF) * 32 + b];
      acc1 = fmaf(__int_as_float(r0.y), s0, acc1);
      acc1 = fmaf(__int_as_float(r1.y), s1, acc1);
      acc1 = fmaf(__int_as_float(r2.y), s2, acc1);
      acc1 = fmaf(__int_as_float(r3.y), s3, acc1);
    }
    for (; e < e1; ++e) {
      int2 r = srt[e];
      acc1 = fmaf(__int_as_float(r.y), spikesT[(size_t)(r.x & 0x3FFF) * 32 + b], acc1);
    }
  }

  // transpose 32x32 tile and write out coalesced
  otile[hw][b]      = acc0;
  otile[hw + 16][b] = acc1;
  __syncthreads();
  const int bb = tid >> 4;              // batch 0..31
  const int cc = (tid & 15) * 2;        // target pair
  float2 o2 = make_float2(otile[cc][bb], otile[cc + 1][bb]);
  *reinterpret_cast<float2*>(&out[(size_t)bb * T_ + k * 32 + cc]) = o2;
}

// ---------------------------------------------------------------------------
__global__ void zero_floats(float* __restrict__ p, int n) {
  int i = blockIdx.x * blockDim.x + threadIdx.x;
  if (i < n) p[i] = 0.0f;
}

// Emergency fallback (tiny ws): direct global atomics, weights inline.
__global__ void naive_kernel(const float* __restrict__ spikes,
                             const float* __restrict__ att,
                             const int*   __restrict__ tgt,
                             const int*   __restrict__ del,
                             float*       __restrict__ out) {
  int i = blockIdx.x * blockDim.x + threadIdx.x;
  if (i >= NEDGES) return;
  int   s = i >> 6;
  int   t = tgt[i];
  float w = edge_weight(att[i], del[i]);
  for (int b = 0; b < B_; ++b)
    unsafeAtomicAdd(&out[(size_t)b * T_ + t], w * spikes[(size_t)b * S_ + s]);
}

// ---------------------------------------------------------------------------
extern "C" void kernel_launch(void* const* d_in, const int* in_sizes, int n_in,
                              void* d_out, int out_size, void* d_ws, size_t ws_size,
                              hipStream_t stream) {
  const float* spikes = (const float*)d_in[0];
  const float* att    = (const float*)d_in[1];
  const int*   tgt    = (const int*)d_in[2];
  const int*   del    = (const int*)d_in[3];
  float*       out    = (float*)d_out;

  const size_t spikesT_bytes = (size_t)S_ * B_ * sizeof(float);         // 2 MB
  const size_t rec_bytes     = (size_t)NEDGES * sizeof(int2);           // 8 MB
  const size_t ofse_bytes    = (size_t)GP_ * NBKT * sizeof(unsigned);   // 1 MB
  const size_t need = spikesT_bytes + rec_bytes + 2 * ofse_bytes + 64;

  if (ws_size < need) {
    zero_floats<<<(B_ * T_ + 255) / 256, 256, 0, stream>>>(out, B_ * T_);
    naive_kernel<<<(NEDGES + 255) / 256, 256, 0, stream>>>(spikes, att, tgt, del, out);
    return;
  }

  char* p = (char*)d_ws;
  float*        spikesT = (float*)p;        p += spikesT_bytes;
  int2*         rec     = (int2*)p;         p += rec_bytes;
  unsigned int* ofse    = (unsigned int*)p; p += ofse_bytes;
  unsigned int* ofseT   = (unsigned int*)p;

  produce<<<GP_, 512, 0, stream>>>(spikes, att, tgt, del, spikesT, rec, ofse);
  transpose_ofse<<<dim3(NBKT / 32, GP_ / 32), dim3(32, 8), 0, stream>>>(ofse, ofseT);
  consume<<<NBKT, 512, 0, stream>>>(rec, ofseT, spikesT, out);
}